// Round 6
// baseline (1565.308 us; speedup 1.0000x reference)
//
#include <hip/hip_runtime.h>

// FusedMoE: T=4096 tokens, H=2048 hidden, I=4096 intermediate, E=8 experts, K=2 top-k.
// Pipeline: routing -> fp32->bf16 pre-convert -> grouped gate_up GEMM (+silu*mul)
//           -> grouped down GEMM (*weight) -> per-token combine of K=2 slots.
// GEMMs: 3-deep software pipeline (T3+T4): BK=32, 3 LDS buffers, ONE raw s_barrier
// per iter with COUNTED s_waitcnt vmcnt(N) (never 0 in steady state) so
// global_load_lds stays in flight ~2 iterations. __syncthreads (vmcnt-0 drain)
// only outside the loop. Hazards: RAW = own-wave vmcnt + barrier join; WAR =
// stage(t+2) issued post-barrier-t, overwrite target buf[(t-1)%3] fully read.
// LDS swizzle (BK=32, 64B rows): chunk c stores c ^ ((row>>1)&3); read quad
// 4*(row&1) + (q ^ ((row>>1)&3)) — measured SQ_LDS_BANK_CONFLICT = 0 (r3/r4).
// launch_bounds: gemm1 (256,2) — dual acc 128 AGPR; (256,3) spills (r3: 3.7GB
// scratch traffic). gemm2 single acc -> (256,3) ok (r5 clean).

#define T_TOK 4096
#define H_DIM 2048
#define I_DIM 4096
#define E_NUM 8
#define K_TOP 2
#define NSLOT (T_TOK * K_TOP)   // 8192 total (token,k) slots

#define BM 128
#define BN 128
#define BK 32                   // K-step per LDS tile (new path)
#define LDKO 72                 // old fallback path only: 64 + 8 bf16 pad

typedef float f32x4 __attribute__((ext_vector_type(4)));
typedef __bf16 bf16x8 __attribute__((ext_vector_type(8)));
typedef unsigned int u32x4 __attribute__((ext_vector_type(4)));

static __device__ __forceinline__ unsigned short f2bf(float f) {
  // round-to-nearest-even fp32 -> bf16 (inputs are finite)
  unsigned u = __float_as_uint(f);
  u += 0x7FFFu + ((u >> 16) & 1u);
  return (unsigned short)(u >> 16);
}

static __device__ __forceinline__ unsigned long long pack4bf(float x0, float x1, float x2, float x3) {
  unsigned lo = (unsigned)f2bf(x0) | ((unsigned)f2bf(x1) << 16);
  unsigned hi = (unsigned)f2bf(x2) | ((unsigned)f2bf(x3) << 16);
  return (unsigned long long)lo | ((unsigned long long)hi << 32);
}

// async 16B/lane global->LDS. LDS dest is wave-uniform base + lane*16 (linear);
// per-lane global source carries the swizzle.
static __device__ __forceinline__ void gload16(void* lds, const void* g) {
  __builtin_amdgcn_global_load_lds(
      (const __attribute__((address_space(1))) unsigned int*)(g),
      (__attribute__((address_space(3))) unsigned int*)(lds), 16, 0, 0);
}

// ---------------------------------------------------------------- routing ---
__global__ void routing_kernel(const float* __restrict__ tw,
                               const int* __restrict__ ids,
                               int* __restrict__ offsets,      // [E+1]
                               int* __restrict__ stok,         // [NSLOT] token id per slot
                               float* __restrict__ sw,         // [NSLOT] renorm weight per slot
                               int* __restrict__ slot_of) {    // [NSLOT] slot per (t,k)
  __shared__ int cnt[E_NUM];
  __shared__ int cur[E_NUM];
  __shared__ int basesh[E_NUM + 1];
  int tid = threadIdx.x;
  if (tid < E_NUM) cnt[tid] = 0;
  __syncthreads();
  for (int idx = tid; idx < NSLOT; idx += 256) atomicAdd(&cnt[ids[idx]], 1);
  __syncthreads();
  if (tid == 0) {
    int acc = 0;
    for (int e = 0; e < E_NUM; ++e) { basesh[e] = acc; acc += cnt[e]; }
    basesh[E_NUM] = acc;
    for (int e = 0; e <= E_NUM; ++e) offsets[e] = basesh[e];
  }
  __syncthreads();
  if (tid < E_NUM) cur[tid] = basesh[tid];
  __syncthreads();
  for (int idx = tid; idx < NSLOT; idx += 256) {
    int t = idx >> 1;
    float w0 = tw[t * 2], w1 = tw[t * 2 + 1];
    float w = ((idx & 1) ? w1 : w0) / (w0 + w1);
    int e = ids[idx];
    int slot = atomicAdd(&cur[e], 1);
    stok[slot] = t;
    sw[slot] = w;
    slot_of[idx] = slot;
  }
}

// ------------------------------------------------------ fp32 -> bf16 convert ---
__global__ __launch_bounds__(256) void cvt_bf16_kernel(const float* __restrict__ in,
                                                       unsigned short* __restrict__ out,
                                                       long long n8) {
  long long stride = (long long)gridDim.x * 256;
  for (long long i = (long long)blockIdx.x * 256 + threadIdx.x; i < n8; i += stride) {
    long long o = i * 8;
    f32x4 v0 = *(const f32x4*)(in + o);
    f32x4 v1 = *(const f32x4*)(in + o + 4);
    unsigned long long p0 = pack4bf(v0[0], v0[1], v0[2], v0[3]);
    unsigned long long p1 = pack4bf(v1[0], v1[1], v1[2], v1[3]);
    u32x4 st;
    st[0] = (unsigned)p0; st[1] = (unsigned)(p0 >> 32);
    st[2] = (unsigned)p1; st[3] = (unsigned)(p1 >> 32);
    *(u32x4*)(out + o) = st;
  }
}

// ------------------------------------------- gate_up GEMM (bf16) + silu*mul ---
// 128x128 act tile, dual acc (gate+up). 3-buffer pipelined BK=32 K-loop.
__global__ __launch_bounds__(256, 2) void gemm1_bf16_kernel(
    const unsigned short* __restrict__ hb,   // hidden bf16 [T][H]
    const unsigned short* __restrict__ gub,  // gate_up bf16 [E][2I][H]
    const int* __restrict__ offsets, const int* __restrict__ stok,
    unsigned short* __restrict__ act) {
  int e = blockIdx.z;
  int base = offsets[e];
  int cnt = offsets[e + 1] - base;
  int m0 = blockIdx.y * BM;
  if (m0 >= cnt) return;
  int n0 = blockIdx.x * BN;
  int rem = cnt - m0;

  __shared__ __attribute__((aligned(16))) unsigned short As[3][BM * BK];
  __shared__ __attribute__((aligned(16))) unsigned short Bg[3][BN * BK];
  __shared__ __attribute__((aligned(16))) unsigned short Bu[3][BN * BK];
  __shared__ int toks[BM];

  int tid = threadIdx.x;
  // safe token for padded rows (block only runs when cnt >= 1)
  if (tid < BM) toks[tid] = (tid < rem) ? stok[base + m0 + tid] : stok[base];
  __syncthreads();

  int lane = tid & 63;
  int wid = tid >> 6;
  int sr = lane >> 2;                                 // row within 16-row staging group
  int scz = (((lane & 3) ^ ((lane >> 3) & 3)) << 3);  // src chunk: c ^ ((row>>1)&3)

  const unsigned short* wrow = gub + (size_t)e * (2 * (size_t)I_DIM) * H_DIM;
  const unsigned short* pa[2];
  const unsigned short* pg[2];
  const unsigned short* pu[2];
  int lb[2];
#pragma unroll
  for (int s = 0; s < 2; ++s) {
    int grp = (wid * 2 + s) * 16;
    int row = grp + sr;
    pa[s] = hb + (size_t)toks[row] * H_DIM + scz;
    pg[s] = wrow + (size_t)(n0 + row) * H_DIM + scz;
    pu[s] = wrow + (size_t)(I_DIM + n0 + row) * H_DIM + scz;
    lb[s] = grp * BK;                    // LDS base in shorts
  }

  int lm = lane & 15;
  int q = lane >> 4;
  int wm = (wid >> 1) * 64;
  int wn = (wid & 1) * 64;
  int rcs = ((q ^ ((lm >> 1) & 3)) << 3);  // read chunk: q ^ ((row>>1)&3)

  f32x4 accg[4][4] = {};
  f32x4 accu[4][4] = {};

  auto stage = [&](int b, int kbo) {
#pragma unroll
    for (int s = 0; s < 2; ++s) {
      gload16(&As[b][lb[s]], pa[s] + kbo);
      gload16(&Bg[b][lb[s]], pg[s] + kbo);
      gload16(&Bu[b][lb[s]], pu[s] + kbo);
    }
  };
  auto compute = [&](int b) {
    bf16x8 a[4], bgf[4], buf_[4];
#pragma unroll
    for (int i = 0; i < 4; ++i)
      a[i] = *(const bf16x8*)&As[b][(wm + i * 16 + lm) * BK + rcs];
#pragma unroll
    for (int j = 0; j < 4; ++j) {
      bgf[j] = *(const bf16x8*)&Bg[b][(wn + j * 16 + lm) * BK + rcs];
      buf_[j] = *(const bf16x8*)&Bu[b][(wn + j * 16 + lm) * BK + rcs];
    }
    __builtin_amdgcn_s_setprio(1);
#pragma unroll
    for (int i = 0; i < 4; ++i)
#pragma unroll
      for (int j = 0; j < 4; ++j) {
        accg[i][j] = __builtin_amdgcn_mfma_f32_16x16x32_bf16(a[i], bgf[j], accg[i][j], 0, 0, 0);
        accu[i][j] = __builtin_amdgcn_mfma_f32_16x16x32_bf16(a[i], buf_[j], accu[i][j], 0, 0, 0);
      }
    __builtin_amdgcn_s_setprio(0);
  };

  // prologue: stage tiles 0 and 1 (6 VMEM instrs per wave each)
  stage(0, 0);
  stage(1, BK);

  int cur = 0;
  // main loop: tiles 0..NT-3; each iter stages tile t+2.
  for (int kb = 0; kb < H_DIM - 2 * BK; kb += BK) {
    // allow newest 6 (tile t+1's loads) outstanding; forces tile t complete
    asm volatile("s_waitcnt vmcnt(6)" ::: "memory");
    __builtin_amdgcn_s_barrier();   // joins per-wave vmcnt states; WAR-safe point
    int nxt = cur + 2; if (nxt >= 3) nxt -= 3;
    stage(nxt, kb + 2 * BK);
    compute(cur);
    cur = (cur + 1 == 3) ? 0 : cur + 1;
  }
  // tail tile NT-2: only tile NT-1's 6 loads may remain outstanding
  asm volatile("s_waitcnt vmcnt(6)" ::: "memory");
  __builtin_amdgcn_s_barrier();
  compute(cur);
  cur = (cur + 1 == 3) ? 0 : cur + 1;
  // tail tile NT-1: drain
  asm volatile("s_waitcnt vmcnt(0)" ::: "memory");
  __builtin_amdgcn_s_barrier();
  compute(cur);

  // epilogue: act = silu(gate)*up, bf16 store. D layout: row=q*4+reg, col=lane&15.
#pragma unroll
  for (int i = 0; i < 4; ++i) {
    int mb = wm + i * 16 + q * 4;
#pragma unroll
    for (int r = 0; r < 4; ++r) {
      int m = mb + r;
      if (m < rem) {
        size_t rowoff = (size_t)(base + m0 + m) * I_DIM + n0;
#pragma unroll
        for (int j = 0; j < 4; ++j) {
          int n = wn + j * 16 + lm;
          float g = accg[i][j][r];
          float u = accu[i][j][r];
          float aa = (g / (1.0f + __expf(-g))) * u;
          act[rowoff + n] = f2bf(aa);
        }
      }
    }
  }
}

// ---------------------------------------------- down GEMM (bf16) * weight ---
__global__ __launch_bounds__(256, 3) void gemm2_bf16_kernel(
    const unsigned short* __restrict__ act, const unsigned short* __restrict__ dwb,
    const int* __restrict__ offsets, const float* __restrict__ sw,
    float* __restrict__ dout) {
  int e = blockIdx.z;
  int base = offsets[e];
  int cnt = offsets[e + 1] - base;
  int m0 = blockIdx.y * BM;
  if (m0 >= cnt) return;
  int n0 = blockIdx.x * BN;
  int rem = cnt - m0;

  __shared__ __attribute__((aligned(16))) unsigned short As[3][BM * BK];
  __shared__ __attribute__((aligned(16))) unsigned short Bs[3][BN * BK];
  __shared__ float wsl[BM];

  int tid = threadIdx.x;
  if (tid < BM) wsl[tid] = (tid < rem) ? sw[base + m0 + tid] : 0.f;
  __syncthreads();

  int lane = tid & 63;
  int wid = tid >> 6;
  int sr = lane >> 2;
  int scz = (((lane & 3) ^ ((lane >> 3) & 3)) << 3);

  const unsigned short* dp = dwb + (size_t)e * ((size_t)H_DIM * I_DIM);
  const unsigned short* pa[2];
  const unsigned short* pb[2];
  int lb[2];
#pragma unroll
  for (int s = 0; s < 2; ++s) {
    int grp = (wid * 2 + s) * 16;
    int row = grp + sr;
    pa[s] = act + (size_t)(base + m0 + row) * I_DIM + scz;
    pb[s] = dp + (size_t)(n0 + row) * I_DIM + scz;
    lb[s] = grp * BK;
  }

  int lm = lane & 15;
  int q = lane >> 4;
  int wm = (wid >> 1) * 64;
  int wn = (wid & 1) * 64;
  int rcs = ((q ^ ((lm >> 1) & 3)) << 3);

  f32x4 acc[4][4] = {};

  auto stage = [&](int b, int kbo) {
#pragma unroll
    for (int s = 0; s < 2; ++s) {
      gload16(&As[b][lb[s]], pa[s] + kbo);
      gload16(&Bs[b][lb[s]], pb[s] + kbo);
    }
  };
  auto compute = [&](int b) {
    bf16x8 a[4], bf[4];
#pragma unroll
    for (int i = 0; i < 4; ++i)
      a[i] = *(const bf16x8*)&As[b][(wm + i * 16 + lm) * BK + rcs];
#pragma unroll
    for (int j = 0; j < 4; ++j)
      bf[j] = *(const bf16x8*)&Bs[b][(wn + j * 16 + lm) * BK + rcs];
    __builtin_amdgcn_s_setprio(1);
#pragma unroll
    for (int i = 0; i < 4; ++i)
#pragma unroll
      for (int j = 0; j < 4; ++j)
        acc[i][j] = __builtin_amdgcn_mfma_f32_16x16x32_bf16(a[i], bf[j], acc[i][j], 0, 0, 0);
    __builtin_amdgcn_s_setprio(0);
  };

  stage(0, 0);
  stage(1, BK);

  int cur = 0;
  for (int kb = 0; kb < I_DIM - 2 * BK; kb += BK) {
    // 4 loads per stage per wave -> allow newest 4 (tile t+1), force tile t
    asm volatile("s_waitcnt vmcnt(4)" ::: "memory");
    __builtin_amdgcn_s_barrier();
    int nxt = cur + 2; if (nxt >= 3) nxt -= 3;
    stage(nxt, kb + 2 * BK);
    compute(cur);
    cur = (cur + 1 == 3) ? 0 : cur + 1;
  }
  asm volatile("s_waitcnt vmcnt(4)" ::: "memory");
  __builtin_amdgcn_s_barrier();
  compute(cur);
  cur = (cur + 1 == 3) ? 0 : cur + 1;
  asm volatile("s_waitcnt vmcnt(0)" ::: "memory");
  __builtin_amdgcn_s_barrier();
  compute(cur);

#pragma unroll
  for (int i = 0; i < 4; ++i) {
    int mb = wm + i * 16 + q * 4;
#pragma unroll
    for (int r = 0; r < 4; ++r) {
      int m = mb + r;
      if (m < rem) {
        float w = wsl[m];
        size_t rowoff = (size_t)(base + m0 + m) * H_DIM + n0;
#pragma unroll
        for (int j = 0; j < 4; ++j)
          dout[rowoff + wn + j * 16 + lm] = acc[i][j][r] * w;
      }
    }
  }
}

// ==================== OLD PATH (fallback if workspace too small) =============
__global__ __launch_bounds__(256, 2) void gemm1_kernel(
    const float* __restrict__ hidden, const float* __restrict__ gu,
    const int* __restrict__ offsets, const int* __restrict__ stok,
    unsigned short* __restrict__ act) {
  int e = blockIdx.z;
  int base = offsets[e];
  int cnt = offsets[e + 1] - base;
  int m0 = blockIdx.y * BM;
  if (m0 >= cnt) return;
  int n0 = blockIdx.x * BN;
  int rem = cnt - m0;

  __shared__ unsigned short As[BM * LDKO];
  __shared__ unsigned short Bg[BM * LDKO];
  __shared__ unsigned short Bu[BM * LDKO];
  __shared__ int toks[BM];

  int tid = threadIdx.x;
  if (tid < BM) toks[tid] = (tid < rem) ? stok[base + m0 + tid] : -1;
  __syncthreads();

  int lane = tid & 63;
  int wid = tid >> 6;
  int wm = (wid >> 1) * 64;
  int wn = (wid & 1) * 64;
  int lm = lane & 15;
  int q = lane >> 4;

  f32x4 accg[4][4] = {};
  f32x4 accu[4][4] = {};
  const float* gup = gu + (size_t)e * (2 * (size_t)I_DIM * H_DIM);

  for (int kb = 0; kb < H_DIM; kb += 64) {
#pragma unroll
    for (int s = 0; s < 8; ++s) {
      int task = tid + s * 256;
      int row = task >> 4;
      int cg = (task & 15) << 2;
      int tok = toks[row];
      float x0 = 0.f, x1 = 0.f, x2 = 0.f, x3 = 0.f;
      if (tok >= 0) {
        f32x4 v = *(const f32x4*)(hidden + (size_t)tok * H_DIM + kb + cg);
        x0 = v[0]; x1 = v[1]; x2 = v[2]; x3 = v[3];
      }
      *(unsigned long long*)&As[row * LDKO + cg] = pack4bf(x0, x1, x2, x3);
    }
#pragma unroll
    for (int s = 0; s < 8; ++s) {
      int task = tid + s * 256;
      int row = task >> 4;
      int cg = (task & 15) << 2;
      f32x4 vg = *(const f32x4*)(gup + (size_t)(n0 + row) * H_DIM + kb + cg);
      f32x4 vu = *(const f32x4*)(gup + (size_t)(I_DIM + n0 + row) * H_DIM + kb + cg);
      *(unsigned long long*)&Bg[row * LDKO + cg] = pack4bf(vg[0], vg[1], vg[2], vg[3]);
      *(unsigned long long*)&Bu[row * LDKO + cg] = pack4bf(vu[0], vu[1], vu[2], vu[3]);
    }
    __syncthreads();
#pragma unroll
    for (int ks = 0; ks < 2; ++ks) {
      int ko = ks * 32 + q * 8;
      bf16x8 a[4], bg[4], bu[4];
#pragma unroll
      for (int i = 0; i < 4; ++i)
        a[i] = *(const bf16x8*)&As[(wm + i * 16 + lm) * LDKO + ko];
#pragma unroll
      for (int j = 0; j < 4; ++j) {
        bg[j] = *(const bf16x8*)&Bg[(wn + j * 16 + lm) * LDKO + ko];
        bu[j] = *(const bf16x8*)&Bu[(wn + j * 16 + lm) * LDKO + ko];
      }
#pragma unroll
      for (int i = 0; i < 4; ++i)
#pragma unroll
        for (int j = 0; j < 4; ++j) {
          accg[i][j] = __builtin_amdgcn_mfma_f32_16x16x32_bf16(a[i], bg[j], accg[i][j], 0, 0, 0);
          accu[i][j] = __builtin_amdgcn_mfma_f32_16x16x32_bf16(a[i], bu[j], accu[i][j], 0, 0, 0);
        }
    }
    __syncthreads();
  }

#pragma unroll
  for (int i = 0; i < 4; ++i) {
    int mb = wm + i * 16 + q * 4;
#pragma unroll
    for (int r = 0; r < 4; ++r) {
      int m = mb + r;
      if (m < rem) {
        size_t rowoff = (size_t)(base + m0 + m) * I_DIM + n0;
#pragma unroll
        for (int j = 0; j < 4; ++j) {
          int n = wn + j * 16 + lm;
          float g = accg[i][j][r];
          float u = accu[i][j][r];
          float aa = (g / (1.0f + __expf(-g))) * u;
          act[rowoff + n] = f2bf(aa);
        }
      }
    }
  }
}

__global__ __launch_bounds__(256, 2) void gemm2_kernel(
    const unsigned short* __restrict__ act, const float* __restrict__ dwn,
    const int* __restrict__ offsets, const float* __restrict__ sw,
    float* __restrict__ dout) {
  int e = blockIdx.z;
  int base = offsets[e];
  int cnt = offsets[e + 1] - base;
  int m0 = blockIdx.y * BM;
  if (m0 >= cnt) return;
  int n0 = blockIdx.x * BN;
  int rem = cnt - m0;

  __shared__ unsigned short As[BM * LDKO];
  __shared__ unsigned short Bs[BM * LDKO];
  __shared__ float wsl[BM];

  int tid = threadIdx.x;
  if (tid < BM) wsl[tid] = (tid < rem) ? sw[base + m0 + tid] : 0.f;

  int lane = tid & 63;
  int wid = tid >> 6;
  int wm = (wid >> 1) * 64;
  int wn = (wid & 1) * 64;
  int lm = lane & 15;
  int q = lane >> 4;

  f32x4 acc[4][4] = {};
  const float* dp = dwn + (size_t)e * ((size_t)H_DIM * I_DIM);
  const unsigned short* ap = act + (size_t)(base + m0) * I_DIM;

  for (int kb = 0; kb < I_DIM; kb += 64) {
#pragma unroll
    for (int s = 0; s < 4; ++s) {
      int task = tid + s * 256;
      int row = task >> 3;
      int cg = (task & 7) << 3;
      u32x4 v = *(const u32x4*)(ap + (size_t)row * I_DIM + kb + cg);
      *(u32x4*)&As[row * LDKO + cg] = v;
    }
#pragma unroll
    for (int s = 0; s < 8; ++s) {
      int task = tid + s * 256;
      int row = task >> 4;
      int cg = (task & 15) << 2;
      f32x4 v = *(const f32x4*)(dp + (size_t)(n0 + row) * I_DIM + kb + cg);
      *(unsigned long long*)&Bs[row * LDKO + cg] = pack4bf(v[0], v[1], v[2], v[3]);
    }
    __syncthreads();
#pragma unroll
    for (int ks = 0; ks < 2; ++ks) {
      int ko = ks * 32 + q * 8;
      bf16x8 a[4], b[4];
#pragma unroll
      for (int i = 0; i < 4; ++i)
        a[i] = *(const bf16x8*)&As[(wm + i * 16 + lm) * LDKO + ko];
#pragma unroll
      for (int j = 0; j < 4; ++j)
        b[j] = *(const bf16x8*)&Bs[(wn + j * 16 + lm) * LDKO + ko];
#pragma unroll
      for (int i = 0; i < 4; ++i)
#pragma unroll
        for (int j = 0; j < 4; ++j)
          acc[i][j] = __builtin_amdgcn_mfma_f32_16x16x32_bf16(a[i], b[j], acc[i][j], 0, 0, 0);
    }
    __syncthreads();
  }

#pragma unroll
  for (int i = 0; i < 4; ++i) {
    int mb = wm + i * 16 + q * 4;
#pragma unroll
    for (int r = 0; r < 4; ++r) {
      int m = mb + r;
      if (m < rem) {
        float w = wsl[m];
        size_t rowoff = (size_t)(base + m0 + m) * H_DIM + n0;
#pragma unroll
        for (int j = 0; j < 4; ++j)
          dout[rowoff + wn + j * 16 + lm] = acc[i][j][r] * w;
      }
    }
  }
}

// ------------------------------------------------------------------ combine ---
__global__ void combine_kernel(const f32x4* __restrict__ dout4,
                               const int* __restrict__ slot_of,
                               f32x4* __restrict__ out4) {
  int idx = blockIdx.x * 256 + threadIdx.x;   // over T*H/4 = 2M
  int t = idx >> 9;                           // H/4 = 512 float4 per token
  int c = idx & 511;
  int s0 = slot_of[t * 2];
  int s1 = slot_of[t * 2 + 1];
  f32x4 r = dout4[(size_t)s0 * 512 + c] + dout4[(size_t)s1 * 512 + c];
  out4[idx] = r;
}

// ----------------------------------------------------------------- launch ---
extern "C" void kernel_launch(void* const* d_in, const int* in_sizes, int n_in,
                              void* d_out, int out_size, void* d_ws, size_t ws_size,
                              hipStream_t stream) {
  const float* hidden = (const float*)d_in[0];
  const float* tw     = (const float*)d_in[1];
  const int*   ids    = (const int*)d_in[2];
  const float* gu     = (const float*)d_in[3];
  const float* dwn    = (const float*)d_in[4];
  float* out = (float*)d_out;
  char* ws = (char*)d_ws;

  // common routing scratch (first 128 KiB)
  int*   offsets = (int*)ws;
  int*   stok    = (int*)(ws + 256);
  float* swp     = (float*)(ws + 256 + 32768);
  int*   slot_of = (int*)(ws + 256 + 65536);
  const size_t base_off = 1 << 17;
  const size_t act_sz   = (size_t)(NSLOT + BM) * I_DIM * 2;    // bf16, +pad rows

  routing_kernel<<<1, 256, 0, stream>>>(tw, ids, offsets, stok, swp, slot_of);

  // new-path layout:
  //   [base_off]                hidden_bf16   16 MiB
  //   [w_off]                   W region     256 MiB:
  //       gemm1 phase: gu_bf16 (full 256 MiB)
  //       gemm2 phase: down_bf16 [0,128MiB) | dout fp32 [128,192MiB)
  //   [w_off + 256MiB]          act bf16     ~65 MiB
  const size_t hb_sz  = (size_t)T_TOK * H_DIM * 2;
  const size_t gu_sz  = (size_t)E_NUM * 2 * (size_t)I_DIM * H_DIM * 2;
  const size_t dwn_sz = (size_t)E_NUM * (size_t)H_DIM * I_DIM * 2;
  const size_t w_off  = base_off + hb_sz;
  const size_t need   = w_off + gu_sz + act_sz;

  if (ws_size >= need) {
    unsigned short* hb   = (unsigned short*)(ws + base_off);
    unsigned short* gub  = (unsigned short*)(ws + w_off);
    unsigned short* dwb  = (unsigned short*)(ws + w_off);            // aliases gub (dead after gemm1)
    float*          dout = (float*)(ws + w_off + dwn_sz);            // aliases gub tail
    unsigned short* act  = (unsigned short*)(ws + w_off + gu_sz);

    cvt_bf16_kernel<<<2048, 256, 0, stream>>>(hidden, hb, (long long)T_TOK * H_DIM / 8);
    cvt_bf16_kernel<<<2048, 256, 0, stream>>>(gu, gub, (long long)E_NUM * 2 * I_DIM * H_DIM / 8);
    gemm1_bf16_kernel<<<dim3(I_DIM / BN, NSLOT / BM, E_NUM), 256, 0, stream>>>(hb, gub, offsets, stok, act);
    cvt_bf16_kernel<<<2048, 256, 0, stream>>>(dwn, dwb, (long long)E_NUM * H_DIM * I_DIM / 8);
    gemm2_bf16_kernel<<<dim3(H_DIM / BN, NSLOT / BM, E_NUM), 256, 0, stream>>>(act, dwb, offsets, swp, dout);
    combine_kernel<<<(T_TOK * H_DIM / 4) / 256, 256, 0, stream>>>((const f32x4*)dout, slot_of, (f32x4*)out);
  } else {
    // fallback: previous fp32-staging path (fits in ~132 MiB)
    unsigned short* act  = (unsigned short*)(ws + base_off);
    float*          dout = (float*)(ws + base_off + act_sz);
    gemm1_kernel<<<dim3(I_DIM / BN, NSLOT / BM, E_NUM), 256, 0, stream>>>(hidden, gu, offsets, stok, act);
    gemm2_kernel<<<dim3(H_DIM / BN, NSLOT / BM, E_NUM), 256, 0, stream>>>(act, dwn, offsets, swp, dout);
    combine_kernel<<<(T_TOK * H_DIM / 4) / 256, 256, 0, stream>>>((const f32x4*)dout, slot_of, (f32x4*)out);
  }
}

// Round 7
// 1486.559 us; speedup vs baseline: 1.0530x; 1.0530x over previous
//
#include <hip/hip_runtime.h>

// FusedMoE: T=4096 tokens, H=2048 hidden, I=4096 intermediate, E=8 experts, K=2 top-k.
// Pipeline: routing -> fp32->bf16 pre-convert -> grouped gate_up GEMM (+silu*mul)
//           -> grouped down GEMM (*weight) -> per-token combine of K=2 slots.
// gemm1: R5 BK=64 structure + A-operand double-buffer with COUNTED vmcnt(4):
//   per iter: stage B(t) [8 loads] + stage A(t+1) [4 loads] -> vmcnt(4) (A(t+1)
//   may stay in flight) -> s_barrier -> compute As[cur],Bg,Bu -> s_barrier.
//   A's drain leaves the critical path; B drains as before. Last iter: vmcnt(0).
// gemm2: BK=128 (32 iters x 64 MFMA — same barrier/MFMA ratio as gemm1; was 2x).
//   Swizzle for 256B rows: store chunk c at c ^ (row&15); read chunk
//   (ks*4+q) ^ lm -> 16 distinct chunks per 16-lane group -> 2-way (free, m136).
// History: BK=32 schedules (dbuf r2/r4, 3-deep counted r6) all ~410us vs 358
// (per-iter fixed cost dominates). gemm1 launch_bounds MUST stay (256,2):
// dual acc = 128 AGPR; (256,3) spills (r3: WRITE 65MB->3.7GB).

#define T_TOK 4096
#define H_DIM 2048
#define I_DIM 4096
#define E_NUM 8
#define K_TOP 2
#define NSLOT (T_TOK * K_TOP)   // 8192 total (token,k) slots

#define BM 128
#define BN 128
#define BK 64
#define BK2 128                 // gemm2 K-step
#define LDKO 72                 // old fallback path only: 64 + 8 bf16 pad

typedef float f32x4 __attribute__((ext_vector_type(4)));
typedef __bf16 bf16x8 __attribute__((ext_vector_type(8)));
typedef unsigned int u32x4 __attribute__((ext_vector_type(4)));

static __device__ __forceinline__ unsigned short f2bf(float f) {
  // round-to-nearest-even fp32 -> bf16 (inputs are finite)
  unsigned u = __float_as_uint(f);
  u += 0x7FFFu + ((u >> 16) & 1u);
  return (unsigned short)(u >> 16);
}

static __device__ __forceinline__ unsigned long long pack4bf(float x0, float x1, float x2, float x3) {
  unsigned lo = (unsigned)f2bf(x0) | ((unsigned)f2bf(x1) << 16);
  unsigned hi = (unsigned)f2bf(x2) | ((unsigned)f2bf(x3) << 16);
  return (unsigned long long)lo | ((unsigned long long)hi << 32);
}

// async 16B/lane global->LDS. LDS dest is wave-uniform base + lane*16 (linear);
// per-lane global source carries the swizzle.
static __device__ __forceinline__ void gload16(void* lds, const void* g) {
  __builtin_amdgcn_global_load_lds(
      (const __attribute__((address_space(1))) unsigned int*)(g),
      (__attribute__((address_space(3))) unsigned int*)(lds), 16, 0, 0);
}

// ---------------------------------------------------------------- routing ---
__global__ void routing_kernel(const float* __restrict__ tw,
                               const int* __restrict__ ids,
                               int* __restrict__ offsets,      // [E+1]
                               int* __restrict__ stok,         // [NSLOT] token id per slot
                               float* __restrict__ sw,         // [NSLOT] renorm weight per slot
                               int* __restrict__ slot_of) {    // [NSLOT] slot per (t,k)
  __shared__ int cnt[E_NUM];
  __shared__ int cur[E_NUM];
  __shared__ int basesh[E_NUM + 1];
  int tid = threadIdx.x;
  if (tid < E_NUM) cnt[tid] = 0;
  __syncthreads();
  for (int idx = tid; idx < NSLOT; idx += 256) atomicAdd(&cnt[ids[idx]], 1);
  __syncthreads();
  if (tid == 0) {
    int acc = 0;
    for (int e = 0; e < E_NUM; ++e) { basesh[e] = acc; acc += cnt[e]; }
    basesh[E_NUM] = acc;
    for (int e = 0; e <= E_NUM; ++e) offsets[e] = basesh[e];
  }
  __syncthreads();
  if (tid < E_NUM) cur[tid] = basesh[tid];
  __syncthreads();
  for (int idx = tid; idx < NSLOT; idx += 256) {
    int t = idx >> 1;
    float w0 = tw[t * 2], w1 = tw[t * 2 + 1];
    float w = ((idx & 1) ? w1 : w0) / (w0 + w1);
    int e = ids[idx];
    int slot = atomicAdd(&cur[e], 1);
    stok[slot] = t;
    sw[slot] = w;
    slot_of[idx] = slot;
  }
}

// ------------------------------------------------------ fp32 -> bf16 convert ---
__global__ __launch_bounds__(256) void cvt_bf16_kernel(const float* __restrict__ in,
                                                       unsigned short* __restrict__ out,
                                                       long long n8) {
  long long stride = (long long)gridDim.x * 256;
  for (long long i = (long long)blockIdx.x * 256 + threadIdx.x; i < n8; i += stride) {
    long long o = i * 8;
    f32x4 v0 = *(const f32x4*)(in + o);
    f32x4 v1 = *(const f32x4*)(in + o + 4);
    unsigned long long p0 = pack4bf(v0[0], v0[1], v0[2], v0[3]);
    unsigned long long p1 = pack4bf(v1[0], v1[1], v1[2], v1[3]);
    u32x4 st;
    st[0] = (unsigned)p0; st[1] = (unsigned)(p0 >> 32);
    st[2] = (unsigned)p1; st[3] = (unsigned)(p1 >> 32);
    *(u32x4*)(out + o) = st;
  }
}

// ------------------------------------------- gate_up GEMM (bf16) + silu*mul ---
// 128x128 act tile, dual acc (gate+up). BK=64, A double-buffered (counted vmcnt).
// LDS row = 64 bf16 = 128B = 8 chunks of 16B; chunk' = chunk ^ (row&7).
__global__ __launch_bounds__(256, 2) void gemm1_bf16_kernel(
    const unsigned short* __restrict__ hb,   // hidden bf16 [T][H]
    const unsigned short* __restrict__ gub,  // gate_up bf16 [E][2I][H]
    const int* __restrict__ offsets, const int* __restrict__ stok,
    unsigned short* __restrict__ act) {
  int e = blockIdx.z;
  int base = offsets[e];
  int cnt = offsets[e + 1] - base;
  int m0 = blockIdx.y * BM;
  if (m0 >= cnt) return;
  int n0 = blockIdx.x * BN;
  int rem = cnt - m0;

  __shared__ __attribute__((aligned(16))) unsigned short As[2][BM * 64];
  __shared__ __attribute__((aligned(16))) unsigned short Bg[BN * 64];
  __shared__ __attribute__((aligned(16))) unsigned short Bu[BN * 64];
  __shared__ int toks[BM];

  int tid = threadIdx.x;
  // safe token for padded rows (block only runs when cnt >= 1)
  if (tid < BM) toks[tid] = (tid < rem) ? stok[base + m0 + tid] : stok[base];
  __syncthreads();

  int lane = tid & 63;
  int wid = tid >> 6;
  int srow = lane >> 3;                  // row within 8-row staging group == row&7
  int scol = ((lane & 7) ^ srow) << 3;   // swizzled source chunk, in shorts

  const unsigned short* wrow = gub + (size_t)e * (2 * (size_t)I_DIM) * H_DIM;
  const unsigned short* pa[4];
  const unsigned short* pg[4];
  const unsigned short* pu[4];
#pragma unroll
  for (int s = 0; s < 4; ++s) {
    int row = wid * 32 + s * 8 + srow;
    pa[s] = hb + (size_t)toks[row] * H_DIM + scol;
    pg[s] = wrow + (size_t)(n0 + row) * H_DIM + scol;
    pu[s] = wrow + (size_t)(I_DIM + n0 + row) * H_DIM + scol;
  }

  int lm = lane & 15;
  int q = lane >> 4;
  int wm = (wid >> 1) * 64;
  int wn = (wid & 1) * 64;
  // swizzled read cols (shorts): chunk (ks*4+q) ^ (lm&7)
  int rc0 = ((q ^ (lm & 7)) << 3);
  int rc1 = (((4 + q) ^ (lm & 7)) << 3);

  f32x4 accg[4][4] = {};
  f32x4 accu[4][4] = {};

  // prologue: stage A tile 0 (4 loads/thread) into As[0]
#pragma unroll
  for (int s = 0; s < 4; ++s)
    gload16(&As[0][(wid * 32 + s * 8) * 64], pa[s]);

  int cur = 0;
  for (int kb = 0; kb < H_DIM; kb += BK) {
    // stage B(t): 8 loads/thread (needed this iter -> drained below)
#pragma unroll
    for (int s = 0; s < 4; ++s) {
      gload16(&Bg[(wid * 32 + s * 8) * 64], pg[s] + kb);
      gload16(&Bu[(wid * 32 + s * 8) * 64], pu[s] + kb);
    }
    if (kb + BK < H_DIM) {
      // stage A(t+1): 4 loads/thread -> allowed to stay in flight (vmcnt 4)
#pragma unroll
      for (int s = 0; s < 4; ++s)
        gload16(&As[cur ^ 1][(wid * 32 + s * 8) * 64], pa[s] + kb + BK);
      __builtin_amdgcn_sched_barrier(0);
      asm volatile("s_waitcnt vmcnt(4)" ::: "memory");
    } else {
      __builtin_amdgcn_sched_barrier(0);
      asm volatile("s_waitcnt vmcnt(0)" ::: "memory");
    }
    __builtin_amdgcn_s_barrier();
    __builtin_amdgcn_sched_barrier(0);
#pragma unroll
    for (int ks = 0; ks < 2; ++ks) {
      int ko = ks ? rc1 : rc0;
      bf16x8 a[4], bg[4], bu[4];
#pragma unroll
      for (int i = 0; i < 4; ++i)
        a[i] = *(const bf16x8*)&As[cur][(wm + i * 16 + lm) * 64 + ko];
#pragma unroll
      for (int j = 0; j < 4; ++j) {
        bg[j] = *(const bf16x8*)&Bg[(wn + j * 16 + lm) * 64 + ko];
        bu[j] = *(const bf16x8*)&Bu[(wn + j * 16 + lm) * 64 + ko];
      }
#pragma unroll
      for (int i = 0; i < 4; ++i)
#pragma unroll
        for (int j = 0; j < 4; ++j) {
          accg[i][j] = __builtin_amdgcn_mfma_f32_16x16x32_bf16(a[i], bg[j], accg[i][j], 0, 0, 0);
          accu[i][j] = __builtin_amdgcn_mfma_f32_16x16x32_bf16(a[i], bu[j], accu[i][j], 0, 0, 0);
        }
    }
    __builtin_amdgcn_sched_barrier(0);
    __builtin_amdgcn_s_barrier();   // protects Bg/Bu + As[cur] overwrite next iter
    cur ^= 1;
  }

  // epilogue: act = silu(gate)*up, bf16 store. D layout: row=q*4+reg, col=lane&15.
#pragma unroll
  for (int i = 0; i < 4; ++i) {
    int mb = wm + i * 16 + q * 4;
#pragma unroll
    for (int r = 0; r < 4; ++r) {
      int m = mb + r;
      if (m < rem) {
        size_t rowoff = (size_t)(base + m0 + m) * I_DIM + n0;
#pragma unroll
        for (int j = 0; j < 4; ++j) {
          int n = wn + j * 16 + lm;
          float g = accg[i][j][r];
          float u = accu[i][j][r];
          float aa = (g / (1.0f + __expf(-g))) * u;
          act[rowoff + n] = f2bf(aa);
        }
      }
    }
  }
}

// ---------------------------------------------- down GEMM (bf16) * weight ---
// BK2=128: 32 iters x 64 MFMA (same barrier/MFMA ratio as gemm1). LDS 64KB ->
// 2 blocks/CU. Rows are 256B = 16 chunks; store chunk c at c ^ (row&15).
__global__ __launch_bounds__(256, 2) void gemm2_bf16_kernel(
    const unsigned short* __restrict__ act, const unsigned short* __restrict__ dwb,
    const int* __restrict__ offsets, const float* __restrict__ sw,
    float* __restrict__ dout) {
  int e = blockIdx.z;
  int base = offsets[e];
  int cnt = offsets[e + 1] - base;
  int m0 = blockIdx.y * BM;
  if (m0 >= cnt) return;
  int n0 = blockIdx.x * BN;
  int rem = cnt - m0;

  __shared__ __attribute__((aligned(16))) unsigned short As[BM * BK2];
  __shared__ __attribute__((aligned(16))) unsigned short Bs[BM * BK2];
  __shared__ float wsl[BM];

  int tid = threadIdx.x;
  if (tid < BM) wsl[tid] = (tid < rem) ? sw[base + m0 + tid] : 0.f;

  int lane = tid & 63;
  int wid = tid >> 6;
  // staging: task = s*256+tid -> row = s*16 + (tid>>4), chunk = tid&15.
  // src chunk' = chunk ^ (row&15) = (tid&15) ^ (tid>>4)  (independent of s).
  int r0 = tid >> 4;                       // 0..15
  int cz = (((tid & 15) ^ r0) << 3);       // swizzled source col, in shorts

  const unsigned short* dp = dwb + (size_t)e * ((size_t)H_DIM * I_DIM);
  const unsigned short* pa0 = act + (size_t)(base + m0 + r0) * I_DIM + cz;
  const unsigned short* pb0 = dp + (size_t)(n0 + r0) * I_DIM + cz;

  int lm = lane & 15;
  int q = lane >> 4;
  int wm = (wid >> 1) * 64;
  int wn = (wid & 1) * 64;

  f32x4 acc[4][4] = {};

  for (int kb = 0; kb < I_DIM; kb += BK2) {
    // 8 sweeps per array; LDS dest linear at (s*256+tid)*16B
#pragma unroll
    for (int s = 0; s < 8; ++s) {
      gload16(&As[(s * 256 + tid) * 8], pa0 + (size_t)s * 16 * I_DIM + kb);
      gload16(&Bs[(s * 256 + tid) * 8], pb0 + (size_t)s * 16 * I_DIM + kb);
    }
    __syncthreads();
#pragma unroll
    for (int ks = 0; ks < 4; ++ks) {
      int ko = (((ks * 4 + q) ^ lm) << 3);   // read chunk (ks*4+q) ^ (row&15=lm)
      bf16x8 a[4], b[4];
#pragma unroll
      for (int i = 0; i < 4; ++i)
        a[i] = *(const bf16x8*)&As[(wm + i * 16 + lm) * BK2 + ko];
#pragma unroll
      for (int j = 0; j < 4; ++j)
        b[j] = *(const bf16x8*)&Bs[(wn + j * 16 + lm) * BK2 + ko];
#pragma unroll
      for (int i = 0; i < 4; ++i)
#pragma unroll
        for (int j = 0; j < 4; ++j)
          acc[i][j] = __builtin_amdgcn_mfma_f32_16x16x32_bf16(a[i], b[j], acc[i][j], 0, 0, 0);
    }
    __syncthreads();
  }

#pragma unroll
  for (int i = 0; i < 4; ++i) {
    int mb = wm + i * 16 + q * 4;
#pragma unroll
    for (int r = 0; r < 4; ++r) {
      int m = mb + r;
      if (m < rem) {
        float w = wsl[m];
        size_t rowoff = (size_t)(base + m0 + m) * H_DIM + n0;
#pragma unroll
        for (int j = 0; j < 4; ++j)
          dout[rowoff + wn + j * 16 + lm] = acc[i][j][r] * w;
      }
    }
  }
}

// ==================== OLD PATH (fallback if workspace too small) =============
__global__ __launch_bounds__(256, 2) void gemm1_kernel(
    const float* __restrict__ hidden, const float* __restrict__ gu,
    const int* __restrict__ offsets, const int* __restrict__ stok,
    unsigned short* __restrict__ act) {
  int e = blockIdx.z;
  int base = offsets[e];
  int cnt = offsets[e + 1] - base;
  int m0 = blockIdx.y * BM;
  if (m0 >= cnt) return;
  int n0 = blockIdx.x * BN;
  int rem = cnt - m0;

  __shared__ unsigned short As[BM * LDKO];
  __shared__ unsigned short Bg[BM * LDKO];
  __shared__ unsigned short Bu[BM * LDKO];
  __shared__ int toks[BM];

  int tid = threadIdx.x;
  if (tid < BM) toks[tid] = (tid < rem) ? stok[base + m0 + tid] : -1;
  __syncthreads();

  int lane = tid & 63;
  int wid = tid >> 6;
  int wm = (wid >> 1) * 64;
  int wn = (wid & 1) * 64;
  int lm = lane & 15;
  int q = lane >> 4;

  f32x4 accg[4][4] = {};
  f32x4 accu[4][4] = {};
  const float* gup = gu + (size_t)e * (2 * (size_t)I_DIM * H_DIM);

  for (int kb = 0; kb < H_DIM; kb += 64) {
#pragma unroll
    for (int s = 0; s < 8; ++s) {
      int task = tid + s * 256;
      int row = task >> 4;
      int cg = (task & 15) << 2;
      int tok = toks[row];
      float x0 = 0.f, x1 = 0.f, x2 = 0.f, x3 = 0.f;
      if (tok >= 0) {
        f32x4 v = *(const f32x4*)(hidden + (size_t)tok * H_DIM + kb + cg);
        x0 = v[0]; x1 = v[1]; x2 = v[2]; x3 = v[3];
      }
      *(unsigned long long*)&As[row * LDKO + cg] = pack4bf(x0, x1, x2, x3);
    }
#pragma unroll
    for (int s = 0; s < 8; ++s) {
      int task = tid + s * 256;
      int row = task >> 4;
      int cg = (task & 15) << 2;
      f32x4 vg = *(const f32x4*)(gup + (size_t)(n0 + row) * H_DIM + kb + cg);
      f32x4 vu = *(const f32x4*)(gup + (size_t)(I_DIM + n0 + row) * H_DIM + kb + cg);
      *(unsigned long long*)&Bg[row * LDKO + cg] = pack4bf(vg[0], vg[1], vg[2], vg[3]);
      *(unsigned long long*)&Bu[row * LDKO + cg] = pack4bf(vu[0], vu[1], vu[2], vu[3]);
    }
    __syncthreads();
#pragma unroll
    for (int ks = 0; ks < 2; ++ks) {
      int ko = ks * 32 + q * 8;
      bf16x8 a[4], bg[4], bu[4];
#pragma unroll
      for (int i = 0; i < 4; ++i)
        a[i] = *(const bf16x8*)&As[(wm + i * 16 + lm) * LDKO + ko];
#pragma unroll
      for (int j = 0; j < 4; ++j) {
        bg[j] = *(const bf16x8*)&Bg[(wn + j * 16 + lm) * LDKO + ko];
        bu[j] = *(const bf16x8*)&Bu[(wn + j * 16 + lm) * LDKO + ko];
      }
#pragma unroll
      for (int i = 0; i < 4; ++i)
#pragma unroll
        for (int j = 0; j < 4; ++j) {
          accg[i][j] = __builtin_amdgcn_mfma_f32_16x16x32_bf16(a[i], bg[j], accg[i][j], 0, 0, 0);
          accu[i][j] = __builtin_amdgcn_mfma_f32_16x16x32_bf16(a[i], bu[j], accu[i][j], 0, 0, 0);
        }
    }
    __syncthreads();
  }

#pragma unroll
  for (int i = 0; i < 4; ++i) {
    int mb = wm + i * 16 + q * 4;
#pragma unroll
    for (int r = 0; r < 4; ++r) {
      int m = mb + r;
      if (m < rem) {
        size_t rowoff = (size_t)(base + m0 + m) * I_DIM + n0;
#pragma unroll
        for (int j = 0; j < 4; ++j) {
          int n = wn + j * 16 + lm;
          float g = accg[i][j][r];
          float u = accu[i][j][r];
          float aa = (g / (1.0f + __expf(-g))) * u;
          act[rowoff + n] = f2bf(aa);
        }
      }
    }
  }
}

__global__ __launch_bounds__(256, 2) void gemm2_kernel(
    const unsigned short* __restrict__ act, const float* __restrict__ dwn,
    const int* __restrict__ offsets, const float* __restrict__ sw,
    float* __restrict__ dout) {
  int e = blockIdx.z;
  int base = offsets[e];
  int cnt = offsets[e + 1] - base;
  int m0 = blockIdx.y * BM;
  if (m0 >= cnt) return;
  int n0 = blockIdx.x * BN;
  int rem = cnt - m0;

  __shared__ unsigned short As[BM * LDKO];
  __shared__ unsigned short Bs[BM * LDKO];
  __shared__ float wsl[BM];

  int tid = threadIdx.x;
  if (tid < BM) wsl[tid] = (tid < rem) ? sw[base + m0 + tid] : 0.f;

  int lane = tid & 63;
  int wid = tid >> 6;
  int wm = (wid >> 1) * 64;
  int wn = (wid & 1) * 64;
  int lm = lane & 15;
  int q = lane >> 4;

  f32x4 acc[4][4] = {};
  const float* dp = dwn + (size_t)e * ((size_t)H_DIM * I_DIM);
  const unsigned short* ap = act + (size_t)(base + m0) * I_DIM;

  for (int kb = 0; kb < I_DIM; kb += 64) {
#pragma unroll
    for (int s = 0; s < 4; ++s) {
      int task = tid + s * 256;
      int row = task >> 3;
      int cg = (task & 7) << 3;
      u32x4 v = *(const u32x4*)(ap + (size_t)row * I_DIM + kb + cg);
      *(u32x4*)&As[row * LDKO + cg] = v;
    }
#pragma unroll
    for (int s = 0; s < 8; ++s) {
      int task = tid + s * 256;
      int row = task >> 4;
      int cg = (task & 15) << 2;
      f32x4 v = *(const f32x4*)(dp + (size_t)(n0 + row) * I_DIM + kb + cg);
      *(unsigned long long*)&Bs[row * LDKO + cg] = pack4bf(v[0], v[1], v[2], v[3]);
    }
    __syncthreads();
#pragma unroll
    for (int ks = 0; ks < 2; ++ks) {
      int ko = ks * 32 + q * 8;
      bf16x8 a[4], b[4];
#pragma unroll
      for (int i = 0; i < 4; ++i)
        a[i] = *(const bf16x8*)&As[(wm + i * 16 + lm) * LDKO + ko];
#pragma unroll
      for (int j = 0; j < 4; ++j)
        b[j] = *(const bf16x8*)&Bs[(wn + j * 16 + lm) * LDKO + ko];
#pragma unroll
      for (int i = 0; i < 4; ++i)
#pragma unroll
        for (int j = 0; j < 4; ++j)
          acc[i][j] = __builtin_amdgcn_mfma_f32_16x16x32_bf16(a[i], b[j], acc[i][j], 0, 0, 0);
    }
    __syncthreads();
  }

#pragma unroll
  for (int i = 0; i < 4; ++i) {
    int mb = wm + i * 16 + q * 4;
#pragma unroll
    for (int r = 0; r < 4; ++r) {
      int m = mb + r;
      if (m < rem) {
        float w = wsl[m];
        size_t rowoff = (size_t)(base + m0 + m) * H_DIM + n0;
#pragma unroll
        for (int j = 0; j < 4; ++j)
          dout[rowoff + wn + j * 16 + lm] = acc[i][j][r] * w;
      }
    }
  }
}

// ------------------------------------------------------------------ combine ---
__global__ void combine_kernel(const f32x4* __restrict__ dout4,
                               const int* __restrict__ slot_of,
                               f32x4* __restrict__ out4) {
  int idx = blockIdx.x * 256 + threadIdx.x;   // over T*H/4 = 2M
  int t = idx >> 9;                           // H/4 = 512 float4 per token
  int c = idx & 511;
  int s0 = slot_of[t * 2];
  int s1 = slot_of[t * 2 + 1];
  f32x4 r = dout4[(size_t)s0 * 512 + c] + dout4[(size_t)s1 * 512 + c];
  out4[idx] = r;
}

// ----------------------------------------------------------------- launch ---
extern "C" void kernel_launch(void* const* d_in, const int* in_sizes, int n_in,
                              void* d_out, int out_size, void* d_ws, size_t ws_size,
                              hipStream_t stream) {
  const float* hidden = (const float*)d_in[0];
  const float* tw     = (const float*)d_in[1];
  const int*   ids    = (const int*)d_in[2];
  const float* gu     = (const float*)d_in[3];
  const float* dwn    = (const float*)d_in[4];
  float* out = (float*)d_out;
  char* ws = (char*)d_ws;

  // common routing scratch (first 128 KiB)
  int*   offsets = (int*)ws;
  int*   stok    = (int*)(ws + 256);
  float* swp     = (float*)(ws + 256 + 32768);
  int*   slot_of = (int*)(ws + 256 + 65536);
  const size_t base_off = 1 << 17;
  const size_t act_sz   = (size_t)(NSLOT + BM) * I_DIM * 2;    // bf16, +pad rows

  routing_kernel<<<1, 256, 0, stream>>>(tw, ids, offsets, stok, swp, slot_of);

  // new-path layout:
  //   [base_off]                hidden_bf16   16 MiB
  //   [w_off]                   W region     256 MiB:
  //       gemm1 phase: gu_bf16 (full 256 MiB)
  //       gemm2 phase: down_bf16 [0,128MiB) | dout fp32 [128,192MiB)
  //   [w_off + 256MiB]          act bf16     ~65 MiB
  const size_t hb_sz  = (size_t)T_TOK * H_DIM * 2;
  const size_t gu_sz  = (size_t)E_NUM * 2 * (size_t)I_DIM * H_DIM * 2;
  const size_t dwn_sz = (size_t)E_NUM * (size_t)H_DIM * I_DIM * 2;
  const size_t w_off  = base_off + hb_sz;
  const size_t need   = w_off + gu_sz + act_sz;

  if (ws_size >= need) {
    unsigned short* hb   = (unsigned short*)(ws + base_off);
    unsigned short* gub  = (unsigned short*)(ws + w_off);
    unsigned short* dwb  = (unsigned short*)(ws + w_off);            // aliases gub (dead after gemm1)
    float*          dout = (float*)(ws + w_off + dwn_sz);            // aliases gub tail
    unsigned short* act  = (unsigned short*)(ws + w_off + gu_sz);

    cvt_bf16_kernel<<<2048, 256, 0, stream>>>(hidden, hb, (long long)T_TOK * H_DIM / 8);
    cvt_bf16_kernel<<<2048, 256, 0, stream>>>(gu, gub, (long long)E_NUM * 2 * I_DIM * H_DIM / 8);
    gemm1_bf16_kernel<<<dim3(I_DIM / BN, NSLOT / BM, E_NUM), 256, 0, stream>>>(hb, gub, offsets, stok, act);
    cvt_bf16_kernel<<<2048, 256, 0, stream>>>(dwn, dwb, (long long)E_NUM * H_DIM * I_DIM / 8);
    gemm2_bf16_kernel<<<dim3(H_DIM / BN, NSLOT / BM, E_NUM), 256, 0, stream>>>(act, dwb, offsets, swp, dout);
    combine_kernel<<<(T_TOK * H_DIM / 4) / 256, 256, 0, stream>>>((const f32x4*)dout, slot_of, (f32x4*)out);
  } else {
    // fallback: previous fp32-staging path (fits in ~132 MiB)
    unsigned short* act  = (unsigned short*)(ws + base_off);
    float*          dout = (float*)(ws + base_off + act_sz);
    gemm1_kernel<<<dim3(I_DIM / BN, NSLOT / BM, E_NUM), 256, 0, stream>>>(hidden, gu, offsets, stok, act);
    gemm2_kernel<<<dim3(H_DIM / BN, NSLOT / BM, E_NUM), 256, 0, stream>>>(act, dwn, offsets, swp, dout);
    combine_kernel<<<(T_TOK * H_DIM / 4) / 256, 256, 0, stream>>>((const f32x4*)dout, slot_of, (f32x4*)out);
  }
}

// Round 8
// 1456.155 us; speedup vs baseline: 1.0750x; 1.0209x over previous
//
#include <hip/hip_runtime.h>

// FusedMoE: T=4096 tokens, H=2048 hidden, I=4096 intermediate, E=8 experts, K=2 top-k.
// Pipeline: routing -> fp32->bf16 pre-convert -> grouped gate_up GEMM (+silu*mul)
//           -> grouped down GEMM (*weight) -> per-token combine of K=2 slots.
// Both GEMMs: BK=64 single-buffered B + DOUBLE-BUFFERED A with counted vmcnt:
//   per iter: stage B(t) -> stage A(t+1) -> s_waitcnt vmcnt(#A-loads) (A(t+1)
//   stays in flight across the barrier) -> s_barrier -> compute -> s_barrier.
//   Proven on gemm1 in r7: 358->330us, MfmaUtil 35.7->38.8, no spill.
// LDS swizzle (BK=64, 128B rows = 8x16B chunks): store chunk c at c ^ (row&7);
//   read chunk (ks*4+q) ^ (lm&7). Measured SQ_LDS_BANK_CONFLICT = 0.
// History: BK=32 schedules (r2/r4/r6) all ~410us (per-iter fixed cost);
//   gemm2 BK=128 (r7) regressed ~33us (64KB LDS -> 2 blocks/CU, was 3).
// launch_bounds: gemm1 MUST be (256,2) — dual acc 128 AGPR + ~108 VGPR > 170
//   cap at 3 waves/EU (r3 spill: WRITE 65MB->3.7GB). gemm2 single acc -> (256,3).

#define T_TOK 4096
#define H_DIM 2048
#define I_DIM 4096
#define E_NUM 8
#define K_TOP 2
#define NSLOT (T_TOK * K_TOP)   // 8192 total (token,k) slots

#define BM 128
#define BN 128
#define BK 64
#define LDKO 72                 // old fallback path only: 64 + 8 bf16 pad

typedef float f32x4 __attribute__((ext_vector_type(4)));
typedef __bf16 bf16x8 __attribute__((ext_vector_type(8)));
typedef unsigned int u32x4 __attribute__((ext_vector_type(4)));

static __device__ __forceinline__ unsigned short f2bf(float f) {
  // round-to-nearest-even fp32 -> bf16 (inputs are finite)
  unsigned u = __float_as_uint(f);
  u += 0x7FFFu + ((u >> 16) & 1u);
  return (unsigned short)(u >> 16);
}

static __device__ __forceinline__ unsigned long long pack4bf(float x0, float x1, float x2, float x3) {
  unsigned lo = (unsigned)f2bf(x0) | ((unsigned)f2bf(x1) << 16);
  unsigned hi = (unsigned)f2bf(x2) | ((unsigned)f2bf(x3) << 16);
  return (unsigned long long)lo | ((unsigned long long)hi << 32);
}

// async 16B/lane global->LDS. LDS dest is wave-uniform base + lane*16 (linear);
// per-lane global source carries the swizzle.
static __device__ __forceinline__ void gload16(void* lds, const void* g) {
  __builtin_amdgcn_global_load_lds(
      (const __attribute__((address_space(1))) unsigned int*)(g),
      (__attribute__((address_space(3))) unsigned int*)(lds), 16, 0, 0);
}

// ---------------------------------------------------------------- routing ---
__global__ void routing_kernel(const float* __restrict__ tw,
                               const int* __restrict__ ids,
                               int* __restrict__ offsets,      // [E+1]
                               int* __restrict__ stok,         // [NSLOT] token id per slot
                               float* __restrict__ sw,         // [NSLOT] renorm weight per slot
                               int* __restrict__ slot_of) {    // [NSLOT] slot per (t,k)
  __shared__ int cnt[E_NUM];
  __shared__ int cur[E_NUM];
  __shared__ int basesh[E_NUM + 1];
  int tid = threadIdx.x;
  if (tid < E_NUM) cnt[tid] = 0;
  __syncthreads();
  for (int idx = tid; idx < NSLOT; idx += 256) atomicAdd(&cnt[ids[idx]], 1);
  __syncthreads();
  if (tid == 0) {
    int acc = 0;
    for (int e = 0; e < E_NUM; ++e) { basesh[e] = acc; acc += cnt[e]; }
    basesh[E_NUM] = acc;
    for (int e = 0; e <= E_NUM; ++e) offsets[e] = basesh[e];
  }
  __syncthreads();
  if (tid < E_NUM) cur[tid] = basesh[tid];
  __syncthreads();
  for (int idx = tid; idx < NSLOT; idx += 256) {
    int t = idx >> 1;
    float w0 = tw[t * 2], w1 = tw[t * 2 + 1];
    float w = ((idx & 1) ? w1 : w0) / (w0 + w1);
    int e = ids[idx];
    int slot = atomicAdd(&cur[e], 1);
    stok[slot] = t;
    sw[slot] = w;
    slot_of[idx] = slot;
  }
}

// ------------------------------------------------------ fp32 -> bf16 convert ---
__global__ __launch_bounds__(256) void cvt_bf16_kernel(const float* __restrict__ in,
                                                       unsigned short* __restrict__ out,
                                                       long long n8) {
  long long stride = (long long)gridDim.x * 256;
  for (long long i = (long long)blockIdx.x * 256 + threadIdx.x; i < n8; i += stride) {
    long long o = i * 8;
    f32x4 v0 = *(const f32x4*)(in + o);
    f32x4 v1 = *(const f32x4*)(in + o + 4);
    unsigned long long p0 = pack4bf(v0[0], v0[1], v0[2], v0[3]);
    unsigned long long p1 = pack4bf(v1[0], v1[1], v1[2], v1[3]);
    u32x4 st;
    st[0] = (unsigned)p0; st[1] = (unsigned)(p0 >> 32);
    st[2] = (unsigned)p1; st[3] = (unsigned)(p1 >> 32);
    *(u32x4*)(out + o) = st;
  }
}

// ------------------------------------------- gate_up GEMM (bf16) + silu*mul ---
// 128x128 act tile, dual acc (gate+up). BK=64, A double-buffered (counted vmcnt).
// Unchanged from r7 (measured 330us, MfmaUtil 38.8, conflicts 0).
__global__ __launch_bounds__(256, 2) void gemm1_bf16_kernel(
    const unsigned short* __restrict__ hb,   // hidden bf16 [T][H]
    const unsigned short* __restrict__ gub,  // gate_up bf16 [E][2I][H]
    const int* __restrict__ offsets, const int* __restrict__ stok,
    unsigned short* __restrict__ act) {
  int e = blockIdx.z;
  int base = offsets[e];
  int cnt = offsets[e + 1] - base;
  int m0 = blockIdx.y * BM;
  if (m0 >= cnt) return;
  int n0 = blockIdx.x * BN;
  int rem = cnt - m0;

  __shared__ __attribute__((aligned(16))) unsigned short As[2][BM * 64];
  __shared__ __attribute__((aligned(16))) unsigned short Bg[BN * 64];
  __shared__ __attribute__((aligned(16))) unsigned short Bu[BN * 64];
  __shared__ int toks[BM];

  int tid = threadIdx.x;
  // safe token for padded rows (block only runs when cnt >= 1)
  if (tid < BM) toks[tid] = (tid < rem) ? stok[base + m0 + tid] : stok[base];
  __syncthreads();

  int lane = tid & 63;
  int wid = tid >> 6;
  int srow = lane >> 3;                  // row within 8-row staging group == row&7
  int scol = ((lane & 7) ^ srow) << 3;   // swizzled source chunk, in shorts

  const unsigned short* wrow = gub + (size_t)e * (2 * (size_t)I_DIM) * H_DIM;
  const unsigned short* pa[4];
  const unsigned short* pg[4];
  const unsigned short* pu[4];
#pragma unroll
  for (int s = 0; s < 4; ++s) {
    int row = wid * 32 + s * 8 + srow;
    pa[s] = hb + (size_t)toks[row] * H_DIM + scol;
    pg[s] = wrow + (size_t)(n0 + row) * H_DIM + scol;
    pu[s] = wrow + (size_t)(I_DIM + n0 + row) * H_DIM + scol;
  }

  int lm = lane & 15;
  int q = lane >> 4;
  int wm = (wid >> 1) * 64;
  int wn = (wid & 1) * 64;
  // swizzled read cols (shorts): chunk (ks*4+q) ^ (lm&7)
  int rc0 = ((q ^ (lm & 7)) << 3);
  int rc1 = (((4 + q) ^ (lm & 7)) << 3);

  f32x4 accg[4][4] = {};
  f32x4 accu[4][4] = {};

  // prologue: stage A tile 0 (4 loads/thread) into As[0]
#pragma unroll
  for (int s = 0; s < 4; ++s)
    gload16(&As[0][(wid * 32 + s * 8) * 64], pa[s]);

  int cur = 0;
  for (int kb = 0; kb < H_DIM; kb += BK) {
    // stage B(t): 8 loads/thread (needed this iter -> drained below)
#pragma unroll
    for (int s = 0; s < 4; ++s) {
      gload16(&Bg[(wid * 32 + s * 8) * 64], pg[s] + kb);
      gload16(&Bu[(wid * 32 + s * 8) * 64], pu[s] + kb);
    }
    if (kb + BK < H_DIM) {
      // stage A(t+1): 4 loads/thread -> allowed to stay in flight (vmcnt 4)
#pragma unroll
      for (int s = 0; s < 4; ++s)
        gload16(&As[cur ^ 1][(wid * 32 + s * 8) * 64], pa[s] + kb + BK);
      __builtin_amdgcn_sched_barrier(0);
      asm volatile("s_waitcnt vmcnt(4)" ::: "memory");
    } else {
      __builtin_amdgcn_sched_barrier(0);
      asm volatile("s_waitcnt vmcnt(0)" ::: "memory");
    }
    __builtin_amdgcn_s_barrier();
    __builtin_amdgcn_sched_barrier(0);
#pragma unroll
    for (int ks = 0; ks < 2; ++ks) {
      int ko = ks ? rc1 : rc0;
      bf16x8 a[4], bg[4], bu[4];
#pragma unroll
      for (int i = 0; i < 4; ++i)
        a[i] = *(const bf16x8*)&As[cur][(wm + i * 16 + lm) * 64 + ko];
#pragma unroll
      for (int j = 0; j < 4; ++j) {
        bg[j] = *(const bf16x8*)&Bg[(wn + j * 16 + lm) * 64 + ko];
        bu[j] = *(const bf16x8*)&Bu[(wn + j * 16 + lm) * 64 + ko];
      }
#pragma unroll
      for (int i = 0; i < 4; ++i)
#pragma unroll
        for (int j = 0; j < 4; ++j) {
          accg[i][j] = __builtin_amdgcn_mfma_f32_16x16x32_bf16(a[i], bg[j], accg[i][j], 0, 0, 0);
          accu[i][j] = __builtin_amdgcn_mfma_f32_16x16x32_bf16(a[i], bu[j], accu[i][j], 0, 0, 0);
        }
    }
    __builtin_amdgcn_sched_barrier(0);
    __builtin_amdgcn_s_barrier();   // protects Bg/Bu + As[cur] overwrite next iter
    cur ^= 1;
  }

  // epilogue: act = silu(gate)*up, bf16 store. D layout: row=q*4+reg, col=lane&15.
#pragma unroll
  for (int i = 0; i < 4; ++i) {
    int mb = wm + i * 16 + q * 4;
#pragma unroll
    for (int r = 0; r < 4; ++r) {
      int m = mb + r;
      if (m < rem) {
        size_t rowoff = (size_t)(base + m0 + m) * I_DIM + n0;
#pragma unroll
        for (int j = 0; j < 4; ++j) {
          int n = wn + j * 16 + lm;
          float g = accg[i][j][r];
          float u = accu[i][j][r];
          float aa = (g / (1.0f + __expf(-g))) * u;
          act[rowoff + n] = f2bf(aa);
        }
      }
    }
  }
}

// ---------------------------------------------- down GEMM (bf16) * weight ---
// BK=64, (256,3) — r5 clean config — plus gemm1's proven A-prefetch:
// stage B(t) [4 loads] -> stage act(t+1) [4 loads] -> vmcnt(4) -> barrier ->
// compute -> barrier. LDS 48.5KB x3 = 145.5 <= 160; regs ~164 <= 170-cap.
__global__ __launch_bounds__(256, 3) void gemm2_bf16_kernel(
    const unsigned short* __restrict__ act, const unsigned short* __restrict__ dwb,
    const int* __restrict__ offsets, const float* __restrict__ sw,
    float* __restrict__ dout) {
  int e = blockIdx.z;
  int base = offsets[e];
  int cnt = offsets[e + 1] - base;
  int m0 = blockIdx.y * BM;
  if (m0 >= cnt) return;
  int n0 = blockIdx.x * BN;
  int rem = cnt - m0;

  __shared__ __attribute__((aligned(16))) unsigned short As[2][BM * 64];
  __shared__ __attribute__((aligned(16))) unsigned short Bs[BN * 64];
  __shared__ float wsl[BM];

  int tid = threadIdx.x;
  if (tid < BM) wsl[tid] = (tid < rem) ? sw[base + m0 + tid] : 0.f;
  __syncthreads();

  int lane = tid & 63;
  int wid = tid >> 6;
  int srow = lane >> 3;
  int scol = ((lane & 7) ^ srow) << 3;

  const unsigned short* dp = dwb + (size_t)e * ((size_t)H_DIM * I_DIM);
  const unsigned short* pa[4];
  const unsigned short* pb[4];
#pragma unroll
  for (int s = 0; s < 4; ++s) {
    int row = wid * 32 + s * 8 + srow;
    pa[s] = act + (size_t)(base + m0 + row) * I_DIM + scol;
    pb[s] = dp + (size_t)(n0 + row) * I_DIM + scol;
  }

  int lm = lane & 15;
  int q = lane >> 4;
  int wm = (wid >> 1) * 64;
  int wn = (wid & 1) * 64;
  int rc0 = ((q ^ (lm & 7)) << 3);
  int rc1 = (((4 + q) ^ (lm & 7)) << 3);

  f32x4 acc[4][4] = {};

  // prologue: stage A (act) tile 0
#pragma unroll
  for (int s = 0; s < 4; ++s)
    gload16(&As[0][(wid * 32 + s * 8) * 64], pa[s]);

  int cur = 0;
  for (int kb = 0; kb < I_DIM; kb += BK) {
    // stage B(t): needed this iter
#pragma unroll
    for (int s = 0; s < 4; ++s)
      gload16(&Bs[(wid * 32 + s * 8) * 64], pb[s] + kb);
    if (kb + BK < I_DIM) {
      // stage A(t+1): stays in flight across the barrier
#pragma unroll
      for (int s = 0; s < 4; ++s)
        gload16(&As[cur ^ 1][(wid * 32 + s * 8) * 64], pa[s] + kb + BK);
      __builtin_amdgcn_sched_barrier(0);
      asm volatile("s_waitcnt vmcnt(4)" ::: "memory");
    } else {
      __builtin_amdgcn_sched_barrier(0);
      asm volatile("s_waitcnt vmcnt(0)" ::: "memory");
    }
    __builtin_amdgcn_s_barrier();
    __builtin_amdgcn_sched_barrier(0);
#pragma unroll
    for (int ks = 0; ks < 2; ++ks) {
      int ko = ks ? rc1 : rc0;
      bf16x8 a[4], b[4];
#pragma unroll
      for (int i = 0; i < 4; ++i)
        a[i] = *(const bf16x8*)&As[cur][(wm + i * 16 + lm) * 64 + ko];
#pragma unroll
      for (int j = 0; j < 4; ++j)
        b[j] = *(const bf16x8*)&Bs[(wn + j * 16 + lm) * 64 + ko];
#pragma unroll
      for (int i = 0; i < 4; ++i)
#pragma unroll
        for (int j = 0; j < 4; ++j)
          acc[i][j] = __builtin_amdgcn_mfma_f32_16x16x32_bf16(a[i], b[j], acc[i][j], 0, 0, 0);
    }
    __builtin_amdgcn_sched_barrier(0);
    __builtin_amdgcn_s_barrier();   // protects Bs + As[cur] overwrite next iter
    cur ^= 1;
  }

#pragma unroll
  for (int i = 0; i < 4; ++i) {
    int mb = wm + i * 16 + q * 4;
#pragma unroll
    for (int r = 0; r < 4; ++r) {
      int m = mb + r;
      if (m < rem) {
        float w = wsl[m];
        size_t rowoff = (size_t)(base + m0 + m) * H_DIM + n0;
#pragma unroll
        for (int j = 0; j < 4; ++j)
          dout[rowoff + wn + j * 16 + lm] = acc[i][j][r] * w;
      }
    }
  }
}

// ==================== OLD PATH (fallback if workspace too small) =============
__global__ __launch_bounds__(256, 2) void gemm1_kernel(
    const float* __restrict__ hidden, const float* __restrict__ gu,
    const int* __restrict__ offsets, const int* __restrict__ stok,
    unsigned short* __restrict__ act) {
  int e = blockIdx.z;
  int base = offsets[e];
  int cnt = offsets[e + 1] - base;
  int m0 = blockIdx.y * BM;
  if (m0 >= cnt) return;
  int n0 = blockIdx.x * BN;
  int rem = cnt - m0;

  __shared__ unsigned short As[BM * LDKO];
  __shared__ unsigned short Bg[BM * LDKO];
  __shared__ unsigned short Bu[BM * LDKO];
  __shared__ int toks[BM];

  int tid = threadIdx.x;
  if (tid < BM) toks[tid] = (tid < rem) ? stok[base + m0 + tid] : -1;
  __syncthreads();

  int lane = tid & 63;
  int wid = tid >> 6;
  int wm = (wid >> 1) * 64;
  int wn = (wid & 1) * 64;
  int lm = lane & 15;
  int q = lane >> 4;

  f32x4 accg[4][4] = {};
  f32x4 accu[4][4] = {};
  const float* gup = gu + (size_t)e * (2 * (size_t)I_DIM * H_DIM);

  for (int kb = 0; kb < H_DIM; kb += 64) {
#pragma unroll
    for (int s = 0; s < 8; ++s) {
      int task = tid + s * 256;
      int row = task >> 4;
      int cg = (task & 15) << 2;
      int tok = toks[row];
      float x0 = 0.f, x1 = 0.f, x2 = 0.f, x3 = 0.f;
      if (tok >= 0) {
        f32x4 v = *(const f32x4*)(hidden + (size_t)tok * H_DIM + kb + cg);
        x0 = v[0]; x1 = v[1]; x2 = v[2]; x3 = v[3];
      }
      *(unsigned long long*)&As[row * LDKO + cg] = pack4bf(x0, x1, x2, x3);
    }
#pragma unroll
    for (int s = 0; s < 8; ++s) {
      int task = tid + s * 256;
      int row = task >> 4;
      int cg = (task & 15) << 2;
      f32x4 vg = *(const f32x4*)(gup + (size_t)(n0 + row) * H_DIM + kb + cg);
      f32x4 vu = *(const f32x4*)(gup + (size_t)(I_DIM + n0 + row) * H_DIM + kb + cg);
      *(unsigned long long*)&Bg[row * LDKO + cg] = pack4bf(vg[0], vg[1], vg[2], vg[3]);
      *(unsigned long long*)&Bu[row * LDKO + cg] = pack4bf(vu[0], vu[1], vu[2], vu[3]);
    }
    __syncthreads();
#pragma unroll
    for (int ks = 0; ks < 2; ++ks) {
      int ko = ks * 32 + q * 8;
      bf16x8 a[4], bg[4], bu[4];
#pragma unroll
      for (int i = 0; i < 4; ++i)
        a[i] = *(const bf16x8*)&As[(wm + i * 16 + lm) * LDKO + ko];
#pragma unroll
      for (int j = 0; j < 4; ++j) {
        bg[j] = *(const bf16x8*)&Bg[(wn + j * 16 + lm) * LDKO + ko];
        bu[j] = *(const bf16x8*)&Bu[(wn + j * 16 + lm) * LDKO + ko];
      }
#pragma unroll
      for (int i = 0; i < 4; ++i)
#pragma unroll
        for (int j = 0; j < 4; ++j) {
          accg[i][j] = __builtin_amdgcn_mfma_f32_16x16x32_bf16(a[i], bg[j], accg[i][j], 0, 0, 0);
          accu[i][j] = __builtin_amdgcn_mfma_f32_16x16x32_bf16(a[i], bu[j], accu[i][j], 0, 0, 0);
        }
    }
    __syncthreads();
  }

#pragma unroll
  for (int i = 0; i < 4; ++i) {
    int mb = wm + i * 16 + q * 4;
#pragma unroll
    for (int r = 0; r < 4; ++r) {
      int m = mb + r;
      if (m < rem) {
        size_t rowoff = (size_t)(base + m0 + m) * I_DIM + n0;
#pragma unroll
        for (int j = 0; j < 4; ++j) {
          int n = wn + j * 16 + lm;
          float g = accg[i][j][r];
          float u = accu[i][j][r];
          float aa = (g / (1.0f + __expf(-g))) * u;
          act[rowoff + n] = f2bf(aa);
        }
      }
    }
  }
}

__global__ __launch_bounds__(256, 2) void gemm2_kernel(
    const unsigned short* __restrict__ act, const float* __restrict__ dwn,
    const int* __restrict__ offsets, const float* __restrict__ sw,
    float* __restrict__ dout) {
  int e = blockIdx.z;
  int base = offsets[e];
  int cnt = offsets[e + 1] - base;
  int m0 = blockIdx.y * BM;
  if (m0 >= cnt) return;
  int n0 = blockIdx.x * BN;
  int rem = cnt - m0;

  __shared__ unsigned short As[BM * LDKO];
  __shared__ unsigned short Bs[BM * LDKO];
  __shared__ float wsl[BM];

  int tid = threadIdx.x;
  if (tid < BM) wsl[tid] = (tid < rem) ? sw[base + m0 + tid] : 0.f;

  int lane = tid & 63;
  int wid = tid >> 6;
  int wm = (wid >> 1) * 64;
  int wn = (wid & 1) * 64;
  int lm = lane & 15;
  int q = lane >> 4;

  f32x4 acc[4][4] = {};
  const float* dp = dwn + (size_t)e * ((size_t)H_DIM * I_DIM);
  const unsigned short* ap = act + (size_t)(base + m0) * I_DIM;

  for (int kb = 0; kb < I_DIM; kb += 64) {
#pragma unroll
    for (int s = 0; s < 4; ++s) {
      int task = tid + s * 256;
      int row = task >> 3;
      int cg = (task & 7) << 3;
      u32x4 v = *(const u32x4*)(ap + (size_t)row * I_DIM + kb + cg);
      *(u32x4*)&As[row * LDKO + cg] = v;
    }
#pragma unroll
    for (int s = 0; s < 8; ++s) {
      int task = tid + s * 256;
      int row = task >> 4;
      int cg = (task & 15) << 2;
      f32x4 v = *(const f32x4*)(dp + (size_t)(n0 + row) * I_DIM + kb + cg);
      *(unsigned long long*)&Bs[row * LDKO + cg] = pack4bf(v[0], v[1], v[2], v[3]);
    }
    __syncthreads();
#pragma unroll
    for (int ks = 0; ks < 2; ++ks) {
      int ko = ks * 32 + q * 8;
      bf16x8 a[4], b[4];
#pragma unroll
      for (int i = 0; i < 4; ++i)
        a[i] = *(const bf16x8*)&As[(wm + i * 16 + lm) * LDKO + ko];
#pragma unroll
      for (int j = 0; j < 4; ++j)
        b[j] = *(const bf16x8*)&Bs[(wn + j * 16 + lm) * LDKO + ko];
#pragma unroll
      for (int i = 0; i < 4; ++i)
#pragma unroll
        for (int j = 0; j < 4; ++j)
          acc[i][j] = __builtin_amdgcn_mfma_f32_16x16x32_bf16(a[i], b[j], acc[i][j], 0, 0, 0);
    }
    __syncthreads();
  }

#pragma unroll
  for (int i = 0; i < 4; ++i) {
    int mb = wm + i * 16 + q * 4;
#pragma unroll
    for (int r = 0; r < 4; ++r) {
      int m = mb + r;
      if (m < rem) {
        float w = wsl[m];
        size_t rowoff = (size_t)(base + m0 + m) * H_DIM + n0;
#pragma unroll
        for (int j = 0; j < 4; ++j)
          dout[rowoff + wn + j * 16 + lm] = acc[i][j][r] * w;
      }
    }
  }
}

// ------------------------------------------------------------------ combine ---
__global__ void combine_kernel(const f32x4* __restrict__ dout4,
                               const int* __restrict__ slot_of,
                               f32x4* __restrict__ out4) {
  int idx = blockIdx.x * 256 + threadIdx.x;   // over T*H/4 = 2M
  int t = idx >> 9;                           // H/4 = 512 float4 per token
  int c = idx & 511;
  int s0 = slot_of[t * 2];
  int s1 = slot_of[t * 2 + 1];
  f32x4 r = dout4[(size_t)s0 * 512 + c] + dout4[(size_t)s1 * 512 + c];
  out4[idx] = r;
}

// ----------------------------------------------------------------- launch ---
extern "C" void kernel_launch(void* const* d_in, const int* in_sizes, int n_in,
                              void* d_out, int out_size, void* d_ws, size_t ws_size,
                              hipStream_t stream) {
  const float* hidden = (const float*)d_in[0];
  const float* tw     = (const float*)d_in[1];
  const int*   ids    = (const int*)d_in[2];
  const float* gu     = (const float*)d_in[3];
  const float* dwn    = (const float*)d_in[4];
  float* out = (float*)d_out;
  char* ws = (char*)d_ws;

  // common routing scratch (first 128 KiB)
  int*   offsets = (int*)ws;
  int*   stok    = (int*)(ws + 256);
  float* swp     = (float*)(ws + 256 + 32768);
  int*   slot_of = (int*)(ws + 256 + 65536);
  const size_t base_off = 1 << 17;
  const size_t act_sz   = (size_t)(NSLOT + BM) * I_DIM * 2;    // bf16, +pad rows

  routing_kernel<<<1, 256, 0, stream>>>(tw, ids, offsets, stok, swp, slot_of);

  // new-path layout:
  //   [base_off]                hidden_bf16   16 MiB
  //   [w_off]                   W region     256 MiB:
  //       gemm1 phase: gu_bf16 (full 256 MiB)
  //       gemm2 phase: down_bf16 [0,128MiB) | dout fp32 [128,192MiB)
  //   [w_off + 256MiB]          act bf16     ~65 MiB
  const size_t hb_sz  = (size_t)T_TOK * H_DIM * 2;
  const size_t gu_sz  = (size_t)E_NUM * 2 * (size_t)I_DIM * H_DIM * 2;
  const size_t dwn_sz = (size_t)E_NUM * (size_t)H_DIM * I_DIM * 2;
  const size_t w_off  = base_off + hb_sz;
  const size_t need   = w_off + gu_sz + act_sz;

  if (ws_size >= need) {
    unsigned short* hb   = (unsigned short*)(ws + base_off);
    unsigned short* gub  = (unsigned short*)(ws + w_off);
    unsigned short* dwb  = (unsigned short*)(ws + w_off);            // aliases gub (dead after gemm1)
    float*          dout = (float*)(ws + w_off + dwn_sz);            // aliases gub tail
    unsigned short* act  = (unsigned short*)(ws + w_off + gu_sz);

    cvt_bf16_kernel<<<2048, 256, 0, stream>>>(hidden, hb, (long long)T_TOK * H_DIM / 8);
    cvt_bf16_kernel<<<2048, 256, 0, stream>>>(gu, gub, (long long)E_NUM * 2 * I_DIM * H_DIM / 8);
    gemm1_bf16_kernel<<<dim3(I_DIM / BN, NSLOT / BM, E_NUM), 256, 0, stream>>>(hb, gub, offsets, stok, act);
    cvt_bf16_kernel<<<2048, 256, 0, stream>>>(dwn, dwb, (long long)E_NUM * H_DIM * I_DIM / 8);
    gemm2_bf16_kernel<<<dim3(H_DIM / BN, NSLOT / BM, E_NUM), 256, 0, stream>>>(act, dwb, offsets, swp, dout);
    combine_kernel<<<(T_TOK * H_DIM / 4) / 256, 256, 0, stream>>>((const f32x4*)dout, slot_of, (f32x4*)out);
  } else {
    // fallback: previous fp32-staging path (fits in ~132 MiB)
    unsigned short* act  = (unsigned short*)(ws + base_off);
    float*          dout = (float*)(ws + base_off + act_sz);
    gemm1_kernel<<<dim3(I_DIM / BN, NSLOT / BM, E_NUM), 256, 0, stream>>>(hidden, gu, offsets, stok, act);
    gemm2_kernel<<<dim3(H_DIM / BN, NSLOT / BM, E_NUM), 256, 0, stream>>>(act, dwn, offsets, swp, dout);
    combine_kernel<<<(T_TOK * H_DIM / 4) / 256, 256, 0, stream>>>((const f32x4*)dout, slot_of, (f32x4*)out);
  }
}